// Round 5
// baseline (825.120 us; speedup 1.0000x reference)
//
#include <hip/hip_runtime.h>
#include <hip/hip_bf16.h>
#include <math.h>

#define Bdim 16
#define Tdim 200
#define Pdim 100
#define EMB  100
#define Ddim 300
#define SKILL 30
#define Qdim 50
#define OUTD 50

// d_out layout (floats), concatenated in reference return order:
// res [B,T,50], res2 [B,T,30], kc_mask [B,T,30], attn [B,T,P,1]
#define OFF_RES   0
#define OFF_RES2  (Bdim*Tdim*OUTD)              // 160000
#define OFF_KC    (OFF_RES2 + Bdim*Tdim*SKILL)  // 256000
#define OFF_ATTN  (OFF_KC + Bdim*Tdim*SKILL)    // 352000

typedef __bf16 bf16x8 __attribute__((ext_vector_type(8)));
typedef __bf16 bf16x4 __attribute__((ext_vector_type(4)));
typedef float  f32x4  __attribute__((ext_vector_type(4)));

// MFMA geometry for the score GEMM
#define BM    128          // rows per block
#define KPAD  320          // padded K (and padded N)
#define ASTR  328          // A row stride in bf16 (656 B -> bank rotation 4)
#define BSTR  40           // B row stride in bf16 (80 B  -> bank rotation 20)
#define TPB   512          // 8 waves

#define NROWS (Bdim*Tdim*Pdim)                  // 320000

__device__ __forceinline__ float fast_tanh(float x) {
    // tanh(x) = 1 - 2/(exp(2x)+1); v_exp + v_rcp, saturates correctly at +-inf
    float t = __expf(2.0f * x);
    return 1.0f - 2.0f * __builtin_amdgcn_rcpf(t + 1.0f);
}

// ---------------------------------------------------------------------------
// Prep: W_trans (300x300 fp32, row-major [k][j]) -> bf16 TRANSPOSED padded
// wbt[j][k], j,k in [0,320), zeros outside 300. 204800 B in d_ws.
// ---------------------------------------------------------------------------
__global__ __launch_bounds__(256) void prep_wbt_kernel(
    const float* __restrict__ Wt, __bf16* __restrict__ wbt)
{
    int id = blockIdx.x * 256 + threadIdx.x;
    if (id >= KPAD * KPAD) return;
    int j = id / KPAD, k = id - j * KPAD;
    float v = (j < Ddim && k < Ddim) ? Wt[k * Ddim + j] : 0.0f;
    wbt[id] = (__bf16)v;
}

// ---------------------------------------------------------------------------
// Kernel A (MFMA): raw attention scores.
// score[m] = tanh(E[m] @ W_trans + b_trans) @ W_att + b_att
// E[m] = [nodes[i0] | nodes[i2] | paths[i1]]  (concat order!)
// Block: 128 rows, 8 waves (2M x 4N). Wave tile: 64 rows x 80 cols
// = 4x5 mfma_f32_16x16x32_bf16 frags, K padded to 320 (10 k-tiles of 32).
// ---------------------------------------------------------------------------
__global__ __launch_bounds__(TPB, 2) void score_mfma_kernel(
    const int*    __restrict__ c2v,
    const float*  __restrict__ en,
    const float*  __restrict__ ep,
    const __bf16* __restrict__ wbt,   // [320][320] transposed bf16 W_trans
    const float*  __restrict__ bt,
    const float*  __restrict__ wa,
    const float*  __restrict__ ba,
    float* __restrict__ scores)
{
    __shared__ __bf16 A_lds[BM * ASTR];           // 83968 B
    __shared__ __bf16 B_lds[2][KPAD * BSTR];      // 2 x 25600 B
    __shared__ int    idx_lds[BM * 3];
    __shared__ float  red_lds[4][BM];             // 2048 B

    const int tid = threadIdx.x;
    const int m0  = blockIdx.x * BM;

    for (int i = tid; i < BM * 3; i += TPB) idx_lds[i] = c2v[(size_t)m0 * 3 + i];
    __syncthreads();

    // ---- stage A: gather fp32 embeddings, convert to bf16 ----
    for (int pos = tid; pos < BM * 75; pos += TPB) {
        int r = pos / 75, q = pos - r * 75;
        int seg = q / 25, qq = q - seg * 25;
        int i0 = idx_lds[r * 3 + 0];
        int i1 = idx_lds[r * 3 + 1];
        int i2 = idx_lds[r * 3 + 2];
        const float* src = (seg == 0) ? en + (size_t)i0 * EMB
                         : (seg == 1) ? en + (size_t)i2 * EMB
                                      : ep + (size_t)i1 * EMB;
        float4 v = ((const float4*)src)[qq];
        bf16x4 b4 = { (__bf16)v.x, (__bf16)v.y, (__bf16)v.z, (__bf16)v.w };
        *(bf16x4*)&A_lds[r * ASTR + seg * 100 + qq * 4] = b4;
    }
    // zero K-pad cols 300..319 (read by last k-tile)
    {
        bf16x4 z4 = { (__bf16)0.f, (__bf16)0.f, (__bf16)0.f, (__bf16)0.f };
        for (int pos = tid; pos < BM * 5; pos += TPB) {
            int r = pos / 5, q = pos - r * 5;
            *(bf16x4*)&A_lds[r * ASTR + 300 + q * 4] = z4;
        }
    }

    // ---- B staging helper (20 KB per k-tile) ----
    auto stageB = [&](int kt, int bsel) {
        const int k0 = kt * 32;
        for (int pos = tid; pos < KPAD * 4; pos += TPB) {
            int j = pos >> 2, ck = pos & 3;
            bf16x8 v = *(const bf16x8*)&wbt[j * KPAD + k0 + ck * 8];
            *(bf16x8*)&B_lds[bsel][j * BSTR + ck * 8] = v;
        }
    };

    stageB(0, 0);
    __syncthreads();

    const int wid = tid >> 6, lane = tid & 63;
    const int wm = wid >> 2, wn = wid & 3;       // 2 x 4 wave grid
    const int lr = lane & 15, lg = lane >> 4;

    f32x4 acc[4][5];
    #pragma unroll
    for (int mf = 0; mf < 4; ++mf)
        #pragma unroll
        for (int nf = 0; nf < 5; ++nf) acc[mf][nf] = (f32x4){0.f, 0.f, 0.f, 0.f};

    int buf = 0;
    for (int kt = 0; kt < 10; ++kt) {
        if (kt < 9) stageB(kt + 1, buf ^ 1);
        const int k0 = kt * 32;
        bf16x8 af[4], bfr[5];
        #pragma unroll
        for (int mf = 0; mf < 4; ++mf)
            af[mf] = *(const bf16x8*)&A_lds[(wm * 64 + mf * 16 + lr) * ASTR + k0 + lg * 8];
        #pragma unroll
        for (int nf = 0; nf < 5; ++nf)
            bfr[nf] = *(const bf16x8*)&B_lds[buf][(wn * 80 + nf * 16 + lr) * BSTR + lg * 8];
        #pragma unroll
        for (int mf = 0; mf < 4; ++mf)
            #pragma unroll
            for (int nf = 0; nf < 5; ++nf)
                acc[mf][nf] = __builtin_amdgcn_mfma_f32_16x16x32_bf16(
                    af[mf], bfr[nf], acc[mf][nf], 0, 0, 0);
        __syncthreads();
        buf ^= 1;
    }

    // ---- epilogue: tanh * W_att, reduce over columns ----
    float btv[5], wav[5];
    #pragma unroll
    for (int nf = 0; nf < 5; ++nf) {
        int c = wn * 80 + nf * 16 + lr;
        bool ok = (c < Ddim);
        btv[nf] = ok ? bt[c] : 0.f;
        wav[nf] = ok ? wa[c] : 0.f;
    }
    #pragma unroll
    for (int mf = 0; mf < 4; ++mf) {
        #pragma unroll
        for (int i = 0; i < 4; ++i) {
            float s = 0.f;
            #pragma unroll
            for (int nf = 0; nf < 5; ++nf)
                s += fast_tanh(acc[mf][nf][i] + btv[nf]) * wav[nf];
            // reduce across the 16-lane column dimension (lane bits 0..3)
            s += __shfl_xor(s, 1, 64);
            s += __shfl_xor(s, 2, 64);
            s += __shfl_xor(s, 4, 64);
            s += __shfl_xor(s, 8, 64);
            if (lr == 0) {
                int r = wm * 64 + mf * 16 + lg * 4 + i;
                red_lds[wn][r] = s;
            }
        }
    }
    __syncthreads();
    for (int r = tid; r < BM; r += TPB) {
        float s = ba[0] + red_lds[0][r] + red_lds[1][r] + red_lds[2][r] + red_lds[3][r];
        scores[m0 + r] = s;
    }
}

// ---------------------------------------------------------------------------
// Kernel B: softmax over the TIME axis, in place on the attn region.
// ---------------------------------------------------------------------------
__global__ __launch_bounds__(64) void softmax_time_kernel(float* __restrict__ a)
{
    const int b = blockIdx.x / Pdim;
    const int p = blockIdx.x - b * Pdim;
    const int lane = threadIdx.x;
    const size_t base = (size_t)b * Tdim * Pdim + p;

    float v[4];
    float m = -1e30f;
    #pragma unroll
    for (int i = 0; i < 4; ++i) {
        int t = lane + i * 64;
        v[i] = (t < Tdim) ? a[base + (size_t)t * Pdim] : -1e30f;
        m = fmaxf(m, v[i]);
    }
    #pragma unroll
    for (int off = 32; off > 0; off >>= 1) m = fmaxf(m, __shfl_xor(m, off, 64));

    float s = 0.f;
    #pragma unroll
    for (int i = 0; i < 4; ++i) {
        int t = lane + i * 64;
        if (t < Tdim) { v[i] = expf(v[i] - m); s += v[i]; }
    }
    #pragma unroll
    for (int off = 32; off > 0; off >>= 1) s += __shfl_xor(s, off, 64);

    const float inv = 1.f / s;
    #pragma unroll
    for (int i = 0; i < 4; ++i) {
        int t = lane + i * 64;
        if (t < Tdim) a[base + (size_t)t * Pdim] = v[i] * inv;
    }
}

// ---------------------------------------------------------------------------
// Kernel C+D v3: per (b,t) block, fp32 table gather with HIGH MLP.
// 512 threads: pg = tid/75 (6 p-groups of 75), ch = tid%75 (float4 chunk of
// the 300-float concat row). Each thread: 17 INDEPENDENT 16 B loads (9+8
// register batches, indices pre-read from LDS), p = pg + 6k.
//   code_vec[c] = sum_p attn[p] * full_embed[p][c]
//   kc = sigmoid(x@W_kc+b_kc); out = cv@W_skill+b_skill;
//   res2 = out * (z_kc>=0); res = sigmoid(res2@W_pred+b_pred)
// ---------------------------------------------------------------------------
__global__ __launch_bounds__(512, 4) void cvpred3_kernel(
    const float* __restrict__ x,
    const int*   __restrict__ c2v,
    const float* __restrict__ en,
    const float* __restrict__ ep,
    const float* __restrict__ attn,
    const float* __restrict__ Wsk, const float* __restrict__ bsk,
    const float* __restrict__ Wkc, const float* __restrict__ bkc,
    const float* __restrict__ Wpr, const float* __restrict__ bpr,
    float* __restrict__ res, float* __restrict__ res2, float* __restrict__ kcm)
{
    const int bt_i = blockIdx.x;           // 0..B*T-1
    const int tid  = threadIdx.x;

    __shared__ int    idx_lds[Pdim * 3];
    __shared__ float  attn_lds[Pdim];
    __shared__ float  x_lds[Qdim];
    __shared__ float4 part_lds[6][76];
    __shared__ float  cv_lds[Ddim];
    __shared__ float  r2_lds[SKILL];

    if (tid < Pdim * 3) idx_lds[tid] = c2v[(size_t)bt_i * (Pdim * 3) + tid];
    if (tid >= 320 && tid < 320 + Pdim) attn_lds[tid - 320] = attn[(size_t)bt_i * Pdim + tid - 320];
    if (tid >= 448 && tid < 448 + Qdim) x_lds[tid - 448] = x[(size_t)bt_i * Qdim + tid - 448];
    __syncthreads();

    const int pg = tid / 75;               // 0..6
    const int ch = tid - pg * 75;          // 0..74

    if (pg < 6) {
        const int seg = ch / 25, cq = ch - seg * 25;
        const float* tab = (seg == 2) ? ep : en;
        const int io = (seg == 0) ? 0 : (seg == 1) ? 2 : 1;

        // pre-read all 17 indices + weights from LDS (hoists lgkm deps)
        int   ri[17];
        float rw[17];
        #pragma unroll
        for (int k = 0; k < 17; ++k) {
            int p = pg + 6 * k;
            bool ok = (p < Pdim);
            ri[k] = idx_lds[(ok ? p : 0) * 3 + io];
            rw[k] = ok ? attn_lds[p] : 0.f;
        }

        float4 acc = {0.f, 0.f, 0.f, 0.f};

        // batch A: 9 independent loads, then FMAs
        {
            float4 va[9];
            #pragma unroll
            for (int k = 0; k < 9; ++k)
                va[k] = *(const float4*)&tab[(size_t)ri[k] * EMB + cq * 4];
            #pragma unroll
            for (int k = 0; k < 9; ++k) {
                acc.x = fmaf(rw[k], va[k].x, acc.x);
                acc.y = fmaf(rw[k], va[k].y, acc.y);
                acc.z = fmaf(rw[k], va[k].z, acc.z);
                acc.w = fmaf(rw[k], va[k].w, acc.w);
            }
        }
        // batch B: 8 independent loads, then FMAs
        {
            float4 vb[8];
            #pragma unroll
            for (int k = 0; k < 8; ++k)
                vb[k] = *(const float4*)&tab[(size_t)ri[k + 9] * EMB + cq * 4];
            #pragma unroll
            for (int k = 0; k < 8; ++k) {
                acc.x = fmaf(rw[k + 9], vb[k].x, acc.x);
                acc.y = fmaf(rw[k + 9], vb[k].y, acc.y);
                acc.z = fmaf(rw[k + 9], vb[k].z, acc.z);
                acc.w = fmaf(rw[k + 9], vb[k].w, acc.w);
            }
        }
        part_lds[pg][ch] = acc;
    }
    __syncthreads();

    if (tid < 75) {
        float4 a0 = part_lds[0][tid], a1 = part_lds[1][tid];
        float4 a2 = part_lds[2][tid], a3 = part_lds[3][tid];
        float4 a4 = part_lds[4][tid], a5 = part_lds[5][tid];
        int c = tid * 4;
        cv_lds[c + 0] = a0.x + a1.x + a2.x + a3.x + a4.x + a5.x;
        cv_lds[c + 1] = a0.y + a1.y + a2.y + a3.y + a4.y + a5.y;
        cv_lds[c + 2] = a0.z + a1.z + a2.z + a3.z + a4.z + a5.z;
        cv_lds[c + 3] = a0.w + a1.w + a2.w + a3.w + a4.w + a5.w;
    }
    __syncthreads();

    if (tid < SKILL) {
        const int s = tid;
        float zk = bkc[s];
        for (int q = 0; q < Qdim; ++q) zk = fmaf(x_lds[q], Wkc[q * SKILL + s], zk);
        float kc = 1.f / (1.f + expf(-zk));
        float o = bsk[s];
        for (int c = 0; c < Ddim; ++c) o = fmaf(cv_lds[c], Wsk[c * SKILL + s], o);
        float r2 = (zk >= 0.f) ? o : 0.f;   // sigmoid(zk)>=0.5 <=> zk>=0
        kcm [(size_t)bt_i * SKILL + s] = kc;
        res2[(size_t)bt_i * SKILL + s] = r2;
        r2_lds[s] = r2;
    }
    __syncthreads();

    if (tid < OUTD) {
        float z = bpr[tid];
        #pragma unroll
        for (int s = 0; s < SKILL; ++s) z = fmaf(r2_lds[s], Wpr[s * OUTD + tid], z);
        res[(size_t)bt_i * OUTD + tid] = 1.f / (1.f + expf(-z));
    }
}

// ---------------------------------------------------------------------------
extern "C" void kernel_launch(void* const* d_in, const int* in_sizes, int n_in,
                              void* d_out, int out_size, void* d_ws, size_t ws_size,
                              hipStream_t stream)
{
    const float* x   = (const float*)d_in[0];
    const int*   c2v = (const int*)  d_in[1];
    const float* en  = (const float*)d_in[2];
    const float* ep  = (const float*)d_in[3];
    const float* Wt  = (const float*)d_in[4];
    const float* bt  = (const float*)d_in[5];
    const float* Wa  = (const float*)d_in[6];
    const float* ba  = (const float*)d_in[7];
    const float* Wsk = (const float*)d_in[8];
    const float* bsk = (const float*)d_in[9];
    const float* Wkc = (const float*)d_in[10];
    const float* bkc = (const float*)d_in[11];
    const float* Wpr = (const float*)d_in[12];
    const float* bpr = (const float*)d_in[13];

    float* out  = (float*)d_out;
    float* res  = out + OFF_RES;
    float* res2 = out + OFF_RES2;
    float* kcm  = out + OFF_KC;
    float* attn = out + OFF_ATTN;

    __bf16* wbt = (__bf16*)d_ws;   // 204800 B

    // P: W_trans -> bf16 transposed padded
    prep_wbt_kernel<<<(KPAD * KPAD + 255) / 256, 256, 0, stream>>>(Wt, wbt);

    // A: raw scores into the attn output region (MFMA)
    score_mfma_kernel<<<NROWS / BM, TPB, 0, stream>>>(
        c2v, en, ep, wbt, bt, Wa, ba, attn);

    // B: softmax over time, in place
    softmax_time_kernel<<<Bdim * Pdim, 64, 0, stream>>>(attn);

    // C+D: code_vectors + heads (high-MLP fp32 gather)
    cvpred3_kernel<<<Bdim * Tdim, 512, 0, stream>>>(
        x, c2v, en, ep, attn, Wsk, bsk, Wkc, bkc, Wpr, bpr, res, res2, kcm);
}

// Round 7
// 404.772 us; speedup vs baseline: 2.0385x; 2.0385x over previous
//
#include <hip/hip_runtime.h>
#include <hip/hip_bf16.h>
#include <math.h>

#define Bdim 16
#define Tdim 200
#define Pdim 100
#define EMB  100
#define Ddim 300
#define SKILL 30
#define Qdim 50
#define OUTD 50

// d_out layout (floats), concatenated in reference return order:
// res [B,T,50], res2 [B,T,30], kc_mask [B,T,30], attn [B,T,P,1]
#define OFF_RES   0
#define OFF_RES2  (Bdim*Tdim*OUTD)              // 160000
#define OFF_KC    (OFF_RES2 + Bdim*Tdim*SKILL)  // 256000
#define OFF_ATTN  (OFF_KC + Bdim*Tdim*SKILL)    // 352000

typedef __bf16 bf16x8 __attribute__((ext_vector_type(8)));
typedef __bf16 bf16x4 __attribute__((ext_vector_type(4)));
typedef float  f32x4  __attribute__((ext_vector_type(4)));

// MFMA geometry for the score GEMM
#define BM    128          // rows per block
#define KPAD  320          // padded K (and padded N)
#define ASTR  328          // A row stride in bf16 (656 B -> bank rotation 4)
#define BSTR  40           // B row stride in bf16 (80 B  -> bank rotation 20)
#define TPB   512          // 8 waves

#define NROWS (Bdim*Tdim*Pdim)                  // 320000
#define WBT_BYTES ((size_t)KPAD*KPAD*2)         // 204800
#define E_BYTES   ((size_t)NROWS*Ddim*2)        // 192,000,000

__device__ __forceinline__ float fast_tanh(float x) {
    float t = __expf(2.0f * x);
    return 1.0f - 2.0f * __builtin_amdgcn_rcpf(t + 1.0f);
}
__device__ __forceinline__ float sigmoidf_(float z) {
    return 1.f / (1.f + expf(-z));
}

// ---------------------------------------------------------------------------
// Prep: W_trans (300x300 fp32, row-major [k][j]) -> bf16 TRANSPOSED padded
// ---------------------------------------------------------------------------
__global__ __launch_bounds__(256) void prep_wbt_kernel(
    const float* __restrict__ Wt, __bf16* __restrict__ wbt)
{
    int id = blockIdx.x * 256 + threadIdx.x;
    if (id >= KPAD * KPAD) return;
    int j = id / KPAD, k = id - j * KPAD;
    float v = (j < Ddim && k < Ddim) ? Wt[k * Ddim + j] : 0.0f;
    wbt[id] = (__bf16)v;
}

// ---------------------------------------------------------------------------
// Kernel A (MFMA): raw attention scores; optional bf16 E spill to ws.
// ---------------------------------------------------------------------------
template <bool WRITE_E>
__global__ __launch_bounds__(TPB, 2) void score_mfma_kernel(
    const int*    __restrict__ c2v,
    const float*  __restrict__ en,
    const float*  __restrict__ ep,
    const __bf16* __restrict__ wbt,
    const float*  __restrict__ bt,
    const float*  __restrict__ wa,
    const float*  __restrict__ ba,
    float* __restrict__ scores,
    __bf16* __restrict__ e_out)
{
    __shared__ __bf16 A_lds[BM * ASTR];           // 83968 B
    __shared__ __bf16 B_lds[2][KPAD * BSTR];      // 2 x 25600 B
    __shared__ int    idx_lds[BM * 3];
    __shared__ float  red_lds[4][BM];

    const int tid = threadIdx.x;
    const int m0  = blockIdx.x * BM;

    for (int i = tid; i < BM * 3; i += TPB) idx_lds[i] = c2v[(size_t)m0 * 3 + i];
    __syncthreads();

    for (int pos = tid; pos < BM * 75; pos += TPB) {
        int r = pos / 75, q = pos - r * 75;
        int seg = q / 25, qq = q - seg * 25;
        int i0 = idx_lds[r * 3 + 0];
        int i1 = idx_lds[r * 3 + 1];
        int i2 = idx_lds[r * 3 + 2];
        const float* src = (seg == 0) ? en + (size_t)i0 * EMB
                         : (seg == 1) ? en + (size_t)i2 * EMB
                                      : ep + (size_t)i1 * EMB;
        float4 v = ((const float4*)src)[qq];
        bf16x4 b4 = { (__bf16)v.x, (__bf16)v.y, (__bf16)v.z, (__bf16)v.w };
        *(bf16x4*)&A_lds[r * ASTR + seg * 100 + qq * 4] = b4;
    }
    {
        bf16x4 z4 = { (__bf16)0.f, (__bf16)0.f, (__bf16)0.f, (__bf16)0.f };
        for (int pos = tid; pos < BM * 5; pos += TPB) {
            int r = pos / 5, q = pos - r * 5;
            *(bf16x4*)&A_lds[r * ASTR + 300 + q * 4] = z4;
        }
    }

    auto stageB = [&](int kt, int bsel) {
        const int k0 = kt * 32;
        for (int pos = tid; pos < KPAD * 4; pos += TPB) {
            int j = pos >> 2, ck = pos & 3;
            bf16x8 v = *(const bf16x8*)&wbt[j * KPAD + k0 + ck * 8];
            *(bf16x8*)&B_lds[bsel][j * BSTR + ck * 8] = v;
        }
    };

    stageB(0, 0);
    __syncthreads();

    if (WRITE_E) {
        for (int pos = tid; pos < BM * 75; pos += TPB) {
            int r = pos / 75, q = pos - r * 75;
            bf16x4 v = *(const bf16x4*)&A_lds[r * ASTR + q * 4];
            *(bf16x4*)&e_out[(size_t)(m0 + r) * Ddim + q * 4] = v;
        }
    }

    const int wid = tid >> 6, lane = tid & 63;
    const int wm = wid >> 2, wn = wid & 3;
    const int lr = lane & 15, lg = lane >> 4;

    f32x4 acc[4][5];
    #pragma unroll
    for (int mf = 0; mf < 4; ++mf)
        #pragma unroll
        for (int nf = 0; nf < 5; ++nf) acc[mf][nf] = (f32x4){0.f, 0.f, 0.f, 0.f};

    int buf = 0;
    for (int kt = 0; kt < 10; ++kt) {
        if (kt < 9) stageB(kt + 1, buf ^ 1);
        const int k0 = kt * 32;
        bf16x8 af[4], bfr[5];
        #pragma unroll
        for (int mf = 0; mf < 4; ++mf)
            af[mf] = *(const bf16x8*)&A_lds[(wm * 64 + mf * 16 + lr) * ASTR + k0 + lg * 8];
        #pragma unroll
        for (int nf = 0; nf < 5; ++nf)
            bfr[nf] = *(const bf16x8*)&B_lds[buf][(wn * 80 + nf * 16 + lr) * BSTR + lg * 8];
        #pragma unroll
        for (int mf = 0; mf < 4; ++mf)
            #pragma unroll
            for (int nf = 0; nf < 5; ++nf)
                acc[mf][nf] = __builtin_amdgcn_mfma_f32_16x16x32_bf16(
                    af[mf], bfr[nf], acc[mf][nf], 0, 0, 0);
        __syncthreads();
        buf ^= 1;
    }

    float btv[5], wav[5];
    #pragma unroll
    for (int nf = 0; nf < 5; ++nf) {
        int c = wn * 80 + nf * 16 + lr;
        bool ok = (c < Ddim);
        btv[nf] = ok ? bt[c] : 0.f;
        wav[nf] = ok ? wa[c] : 0.f;
    }
    #pragma unroll
    for (int mf = 0; mf < 4; ++mf) {
        #pragma unroll
        for (int i = 0; i < 4; ++i) {
            float s = 0.f;
            #pragma unroll
            for (int nf = 0; nf < 5; ++nf)
                s += fast_tanh(acc[mf][nf][i] + btv[nf]) * wav[nf];
            s += __shfl_xor(s, 1, 64);
            s += __shfl_xor(s, 2, 64);
            s += __shfl_xor(s, 4, 64);
            s += __shfl_xor(s, 8, 64);
            if (lr == 0) {
                int r = wm * 64 + mf * 16 + lg * 4 + i;
                red_lds[wn][r] = s;
            }
        }
    }
    __syncthreads();
    for (int r = tid; r < BM; r += TPB) {
        float s = ba[0] + red_lds[0][r] + red_lds[1][r] + red_lds[2][r] + red_lds[3][r];
        scores[m0 + r] = s;
    }
}

// ---------------------------------------------------------------------------
// Kernel B: softmax over the TIME axis, in place on the attn region.
// ---------------------------------------------------------------------------
__global__ __launch_bounds__(64) void softmax_time_kernel(float* __restrict__ a)
{
    const int b = blockIdx.x / Pdim;
    const int p = blockIdx.x - b * Pdim;
    const int lane = threadIdx.x;
    const size_t base = (size_t)b * Tdim * Pdim + p;

    float v[4];
    float m = -1e30f;
    #pragma unroll
    for (int i = 0; i < 4; ++i) {
        int t = lane + i * 64;
        v[i] = (t < Tdim) ? a[base + (size_t)t * Pdim] : -1e30f;
        m = fmaxf(m, v[i]);
    }
    #pragma unroll
    for (int off = 32; off > 0; off >>= 1) m = fmaxf(m, __shfl_xor(m, off, 64));

    float s = 0.f;
    #pragma unroll
    for (int i = 0; i < 4; ++i) {
        int t = lane + i * 64;
        if (t < Tdim) { v[i] = expf(v[i] - m); s += v[i]; }
    }
    #pragma unroll
    for (int off = 32; off > 0; off >>= 1) s += __shfl_xor(s, off, 64);

    const float inv = 1.f / s;
    #pragma unroll
    for (int i = 0; i < 4; ++i) {
        int t = lane + i * 64;
        if (t < Tdim) a[base + (size_t)t * Pdim] = v[i] * inv;
    }
}

// ---------------------------------------------------------------------------
// Kernel C+D v4: weights staged to LDS, ALL dot products lane-parallel.
// USE_E: stream bf16 E rows from ws (pre-issued into regs before barrier 1).
// else: fp32 table gather (register-batched).
// Layout per block (512 thr): pg=tid/75 (6 groups), ch=tid%75 (float4 chunk).
// MLP: o[s]: 30 s x 16 lanes (19 LDS iters, shfl-reduce); zk[s]: 30 x 8;
// pred[o]: 50 x 8. No serial global-load chains anywhere.
// ---------------------------------------------------------------------------
template <bool USE_E>
__global__ __launch_bounds__(512, 4) void cvpred4_kernel(
    const float*  __restrict__ x,
    const int*    __restrict__ c2v,
    const float*  __restrict__ en,
    const float*  __restrict__ ep,
    const __bf16* __restrict__ E,
    const float*  __restrict__ attn,
    const float* __restrict__ Wsk, const float* __restrict__ bsk,
    const float* __restrict__ Wkc, const float* __restrict__ bkc,
    const float* __restrict__ Wpr, const float* __restrict__ bpr,
    float* __restrict__ res, float* __restrict__ res2, float* __restrict__ kcm)
{
    const int bt_i = blockIdx.x;           // 0..B*T-1
    const int tid  = threadIdx.x;

    __shared__ float  wsk_lds[Ddim * SKILL];   // 36000 B
    __shared__ float  wkc_lds[Qdim * SKILL];   //  6000 B
    __shared__ float  wpr_lds[SKILL * OUTD];   //  6000 B
    __shared__ int    idx_lds[Pdim * 3];
    __shared__ float  attn_lds[Pdim];
    __shared__ float  x_lds[Qdim];
    __shared__ float4 part_lds[6][76];
    __shared__ float  cv_lds[Ddim];
    __shared__ float  zk_lds[SKILL], o_lds[SKILL], r2_lds[SKILL];

    const int pg = tid / 75;               // 0..6 (6 = inactive)
    const int ch = tid - pg * 75;          // 0..74

    // ---- phase 0: stage weights + per-bt vectors (all independent) ----
    for (int i = tid; i < (Ddim * SKILL) / 4; i += 512)
        ((float4*)wsk_lds)[i] = ((const float4*)Wsk)[i];
    for (int i = tid; i < (Qdim * SKILL) / 4; i += 512)
        ((float4*)wkc_lds)[i] = ((const float4*)Wkc)[i];
    for (int i = tid; i < (SKILL * OUTD) / 4; i += 512)
        ((float4*)wpr_lds)[i] = ((const float4*)Wpr)[i];
    if (!USE_E) {
        if (tid < Pdim * 3) idx_lds[tid] = c2v[(size_t)bt_i * (Pdim * 3) + tid];
    }
    if (tid >= 320 && tid < 320 + Pdim) attn_lds[tid - 320] = attn[(size_t)bt_i * Pdim + tid - 320];
    if (tid >= 448 && tid < 448 + Qdim) x_lds[tid - 448] = x[(size_t)bt_i * Qdim + tid - 448];

    // USE_E: pre-issue the 17 E loads into regs BEFORE the barrier so their
    // latency hides under the weight staging + barrier wait.
    bf16x4 ev[17];
    if (USE_E && pg < 6) {
        const __bf16* base = E + (size_t)bt_i * (Pdim * Ddim) + ch * 4;
        #pragma unroll
        for (int k = 0; k < 17; ++k) {
            int p = pg + 6 * k;
            if (p < Pdim) ev[k] = *(const bf16x4*)(base + p * Ddim);
        }
    }
    __syncthreads();

    // ---- phase 1: weighted sum over p -> part_lds ----
    if (pg < 6) {
        float4 acc = {0.f, 0.f, 0.f, 0.f};
        if (USE_E) {
            #pragma unroll
            for (int k = 0; k < 17; ++k) {
                int p = pg + 6 * k;
                if (p < Pdim) {
                    float a = attn_lds[p];
                    acc.x = fmaf(a, (float)ev[k].x, acc.x);
                    acc.y = fmaf(a, (float)ev[k].y, acc.y);
                    acc.z = fmaf(a, (float)ev[k].z, acc.z);
                    acc.w = fmaf(a, (float)ev[k].w, acc.w);
                }
            }
        } else {
            const int seg = ch / 25, cq = ch - seg * 25;
            const float* tab = (seg == 2) ? ep : en;
            const int io = (seg == 0) ? 0 : (seg == 1) ? 2 : 1;
            int   ri[17];
            float rw[17];
            #pragma unroll
            for (int k = 0; k < 17; ++k) {
                int p = pg + 6 * k;
                bool ok = (p < Pdim);
                ri[k] = idx_lds[(ok ? p : 0) * 3 + io];
                rw[k] = ok ? attn_lds[p] : 0.f;
            }
            {
                float4 va[9];
                #pragma unroll
                for (int k = 0; k < 9; ++k)
                    va[k] = *(const float4*)&tab[(size_t)ri[k] * EMB + cq * 4];
                #pragma unroll
                for (int k = 0; k < 9; ++k) {
                    acc.x = fmaf(rw[k], va[k].x, acc.x);
                    acc.y = fmaf(rw[k], va[k].y, acc.y);
                    acc.z = fmaf(rw[k], va[k].z, acc.z);
                    acc.w = fmaf(rw[k], va[k].w, acc.w);
                }
            }
            {
                float4 vb[8];
                #pragma unroll
                for (int k = 0; k < 8; ++k)
                    vb[k] = *(const float4*)&tab[(size_t)ri[k + 9] * EMB + cq * 4];
                #pragma unroll
                for (int k = 0; k < 8; ++k) {
                    acc.x = fmaf(rw[k + 9], vb[k].x, acc.x);
                    acc.y = fmaf(rw[k + 9], vb[k].y, acc.y);
                    acc.z = fmaf(rw[k + 9], vb[k].z, acc.z);
                    acc.w = fmaf(rw[k + 9], vb[k].w, acc.w);
                }
            }
        }
        part_lds[pg][ch] = acc;
    }
    __syncthreads();

    // ---- phase 2: reduce 6 p-groups -> cv_lds ----
    if (tid < 75) {
        float4 a0 = part_lds[0][tid], a1 = part_lds[1][tid];
        float4 a2 = part_lds[2][tid], a3 = part_lds[3][tid];
        float4 a4 = part_lds[4][tid], a5 = part_lds[5][tid];
        int c = tid * 4;
        cv_lds[c + 0] = a0.x + a1.x + a2.x + a3.x + a4.x + a5.x;
        cv_lds[c + 1] = a0.y + a1.y + a2.y + a3.y + a4.y + a5.y;
        cv_lds[c + 2] = a0.z + a1.z + a2.z + a3.z + a4.z + a5.z;
        cv_lds[c + 3] = a0.w + a1.w + a2.w + a3.w + a4.w + a5.w;
    }
    __syncthreads();

    // ---- phase 3: lane-parallel dot products (all LDS reads) ----
    if (tid < 480) {                       // o[s] = cv . Wsk[:,s]  (30 x 16)
        const int s = tid >> 4, l = tid & 15;
        float o = 0.f;
        #pragma unroll
        for (int j = 0; j < 19; ++j) {
            int c = l + 16 * j;
            if (c < Ddim) o = fmaf(cv_lds[c], wsk_lds[c * SKILL + s], o);
        }
        o += __shfl_xor(o, 8, 64);
        o += __shfl_xor(o, 4, 64);
        o += __shfl_xor(o, 2, 64);
        o += __shfl_xor(o, 1, 64);
        if (l == 0) o_lds[s] = o + bsk[s];
    }
    if (tid < 240) {                       // zk[s] = x . Wkc[:,s]  (30 x 8)
        const int s = tid >> 3, l = tid & 7;
        float zk = 0.f;
        #pragma unroll
        for (int j = 0; j < 7; ++j) {
            int q = l + 8 * j;
            if (q < Qdim) zk = fmaf(x_lds[q], wkc_lds[q * SKILL + s], zk);
        }
        zk += __shfl_xor(zk, 4, 64);
        zk += __shfl_xor(zk, 2, 64);
        zk += __shfl_xor(zk, 1, 64);
        if (l == 0) zk_lds[s] = zk + bkc[s];
    }
    __syncthreads();

    // ---- phase 4: gate + writes ----
    if (tid < SKILL) {
        float zk = zk_lds[tid];
        float r2 = (zk >= 0.f) ? o_lds[tid] : 0.f;  // sigmoid(zk)>=0.5 <=> zk>=0
        kcm [(size_t)bt_i * SKILL + tid] = sigmoidf_(zk);
        res2[(size_t)bt_i * SKILL + tid] = r2;
        r2_lds[tid] = r2;
    }
    __syncthreads();

    // ---- phase 5: res[o] = sigmoid(r2 . Wpr[:,o] + bpr)  (50 x 8) ----
    if (tid < 400) {
        const int od = tid >> 3, l = tid & 7;
        float z = 0.f;
        #pragma unroll
        for (int j = 0; j < 4; ++j) {
            int s = l + 8 * j;
            if (s < SKILL) z = fmaf(r2_lds[s], wpr_lds[s * OUTD + od], z);
        }
        z += __shfl_xor(z, 4, 64);
        z += __shfl_xor(z, 2, 64);
        z += __shfl_xor(z, 1, 64);
        if (l == 0) res[(size_t)bt_i * OUTD + od] = sigmoidf_(z + bpr[od]);
    }
}

// ---------------------------------------------------------------------------
extern "C" void kernel_launch(void* const* d_in, const int* in_sizes, int n_in,
                              void* d_out, int out_size, void* d_ws, size_t ws_size,
                              hipStream_t stream)
{
    const float* x   = (const float*)d_in[0];
    const int*   c2v = (const int*)  d_in[1];
    const float* en  = (const float*)d_in[2];
    const float* ep  = (const float*)d_in[3];
    const float* Wt  = (const float*)d_in[4];
    const float* bt  = (const float*)d_in[5];
    const float* Wa  = (const float*)d_in[6];
    const float* ba  = (const float*)d_in[7];
    const float* Wsk = (const float*)d_in[8];
    const float* bsk = (const float*)d_in[9];
    const float* Wkc = (const float*)d_in[10];
    const float* bkc = (const float*)d_in[11];
    const float* Wpr = (const float*)d_in[12];
    const float* bpr = (const float*)d_in[13];

    float* out  = (float*)d_out;
    float* res  = out + OFF_RES;
    float* res2 = out + OFF_RES2;
    float* kcm  = out + OFF_KC;
    float* attn = out + OFF_ATTN;

    __bf16* wbt  = (__bf16*)d_ws;                       // 204800 B
    __bf16* e_ws = (__bf16*)((char*)d_ws + WBT_BYTES);  // 192 MB bf16 E spill

    const bool use_e = ws_size >= WBT_BYTES + E_BYTES;

    prep_wbt_kernel<<<(KPAD * KPAD + 255) / 256, 256, 0, stream>>>(Wt, wbt);

    if (use_e)
        score_mfma_kernel<true><<<NROWS / BM, TPB, 0, stream>>>(
            c2v, en, ep, wbt, bt, Wa, ba, attn, e_ws);
    else
        score_mfma_kernel<false><<<NROWS / BM, TPB, 0, stream>>>(
            c2v, en, ep, wbt, bt, Wa, ba, attn, e_ws);

    softmax_time_kernel<<<Bdim * Pdim, 64, 0, stream>>>(attn);

    if (use_e)
        cvpred4_kernel<true><<<Bdim * Tdim, 512, 0, stream>>>(
            x, c2v, en, ep, e_ws, attn, Wsk, bsk, Wkc, bkc, Wpr, bpr, res, res2, kcm);
    else
        cvpred4_kernel<false><<<Bdim * Tdim, 512, 0, stream>>>(
            x, c2v, en, ep, e_ws, attn, Wsk, bsk, Wkc, bkc, Wpr, bpr, res, res2, kcm);
}

// Round 8
// 354.167 us; speedup vs baseline: 2.3298x; 1.1429x over previous
//
#include <hip/hip_runtime.h>
#include <hip/hip_bf16.h>
#include <math.h>

#define Bdim 16
#define Tdim 200
#define Pdim 100
#define EMB  100
#define Ddim 300
#define SKILL 30
#define Qdim 50
#define OUTD 50

// d_out layout (floats), concatenated in reference return order:
// res [B,T,50], res2 [B,T,30], kc_mask [B,T,30], attn [B,T,P,1]
#define OFF_RES   0
#define OFF_RES2  (Bdim*Tdim*OUTD)              // 160000
#define OFF_KC    (OFF_RES2 + Bdim*Tdim*SKILL)  // 256000
#define OFF_ATTN  (OFF_KC + Bdim*Tdim*SKILL)    // 352000

typedef __bf16 bf16x8 __attribute__((ext_vector_type(8)));
typedef __bf16 bf16x4 __attribute__((ext_vector_type(4)));
typedef float  f32x4  __attribute__((ext_vector_type(4)));

// MFMA geometry for the score GEMM
#define BM    128          // rows per block
#define KPAD  320          // padded K (and padded N) of wbt
#define ASTR  312          // A row stride in bf16 (624 B -> 2-way bank alias, free)
#define TPB   512          // 8 waves

#define NROWS (Bdim*Tdim*Pdim)                  // 320000
#define WBT_BYTES ((size_t)KPAD*KPAD*2)         // 204800
#define E_BYTES   ((size_t)NROWS*Ddim*2)        // 192,000,000

__device__ __forceinline__ float fast_tanh(float x) {
    float t = __expf(2.0f * x);
    return 1.0f - 2.0f * __builtin_amdgcn_rcpf(t + 1.0f);
}
__device__ __forceinline__ float sigmoidf_(float z) {
    return 1.f / (1.f + expf(-z));
}

// ---------------------------------------------------------------------------
// Prep: W_trans (300x300 fp32, row-major [k][j]) -> bf16 TRANSPOSED padded
// wbt[j][k], zeros outside 300 (both j and k) -- the k-pad zeros are what
// make the A-side garbage reads harmless in the GEMM.
// ---------------------------------------------------------------------------
__global__ __launch_bounds__(256) void prep_wbt_kernel(
    const float* __restrict__ Wt, __bf16* __restrict__ wbt)
{
    int id = blockIdx.x * 256 + threadIdx.x;
    if (id >= KPAD * KPAD) return;
    int j = id / KPAD, k = id - j * KPAD;
    float v = (j < Ddim && k < Ddim) ? Wt[k * Ddim + j] : 0.0f;
    wbt[id] = (__bf16)v;
}

// ---------------------------------------------------------------------------
// Kernel A (MFMA): raw attention scores; bf16 E spill to ws.
// score[m] = tanh(E[m] @ W_trans + b_trans) @ W_att + b_att
// v2 structure: NO B_lds (B fragments read straight from L2-resident wbt),
// barrier-free K-loop, LDS trimmed to exactly 80 KB -> 2 blocks/CU.
// 8 waves (2M x 4N), wave tile 64 rows x 80 cols, 4x5 16x16x32 frags.
// ---------------------------------------------------------------------------
template <bool WRITE_E>
__global__ __launch_bounds__(TPB, 4) void score_mfma_kernel(
    const int*    __restrict__ c2v,
    const float*  __restrict__ en,
    const float*  __restrict__ ep,
    const __bf16* __restrict__ wbt,
    const float*  __restrict__ bt,
    const float*  __restrict__ wa,
    const float*  __restrict__ ba,
    float* __restrict__ scores,
    __bf16* __restrict__ e_out)
{
    __shared__ __align__(16) __bf16 A_lds[BM * ASTR];   // 79872 B
    __shared__ __align__(16) char   aux_lds[2048];      // idx (early) / red (late)
    int*  idx_lds = (int*)aux_lds;                      // [BM*3] = 1536 B
    float (*red_lds)[BM] = (float (*)[BM])aux_lds;      // [4][BM] = 2048 B

    const int tid = threadIdx.x;
    const int m0  = blockIdx.x * BM;

    for (int i = tid; i < BM * 3; i += TPB) idx_lds[i] = c2v[(size_t)m0 * 3 + i];
    __syncthreads();

    // ---- gather fp32 embeddings -> bf16 A tile ----
    for (int pos = tid; pos < BM * 75; pos += TPB) {
        int r = pos / 75, q = pos - r * 75;
        int seg = q / 25, qq = q - seg * 25;
        int i0 = idx_lds[r * 3 + 0];
        int i1 = idx_lds[r * 3 + 1];
        int i2 = idx_lds[r * 3 + 2];
        const float* src = (seg == 0) ? en + (size_t)i0 * EMB
                         : (seg == 1) ? en + (size_t)i2 * EMB
                                      : ep + (size_t)i1 * EMB;
        float4 v = ((const float4*)src)[qq];
        bf16x4 b4 = { (__bf16)v.x, (__bf16)v.y, (__bf16)v.z, (__bf16)v.w };
        *(bf16x4*)&A_lds[r * ASTR + seg * 100 + qq * 4] = b4;
    }
    // zero pad cols 300..311 (NaN hygiene: uninitialized LDS could be NaN,
    // and NaN * 0 = NaN would poison the accumulator)
    {
        bf16x4 z4 = {};
        for (int pos = tid; pos < BM * 3; pos += TPB) {
            int r = pos / 3, q = pos - r * 3;
            *(bf16x4*)&A_lds[r * ASTR + 300 + q * 4] = z4;
        }
    }
    __syncthreads();

    // ---- spill bf16 E tile linearly (fire-and-forget, overlaps K-loop) ----
    if (WRITE_E) {
        for (int pos = tid; pos < BM * 75; pos += TPB) {
            int r = pos / 75, q = pos - r * 75;
            bf16x4 v = *(const bf16x4*)&A_lds[r * ASTR + q * 4];
            *(bf16x4*)&e_out[(size_t)(m0 + r) * Ddim + q * 4] = v;
        }
    }

    const int wid = tid >> 6, lane = tid & 63;
    const int wm = wid >> 2, wn = wid & 3;       // 2 x 4 wave grid
    const int lr = lane & 15, lg = lane >> 4;

    f32x4 acc[4][5];
    #pragma unroll
    for (int mf = 0; mf < 4; ++mf)
        #pragma unroll
        for (int nf = 0; nf < 5; ++nf) acc[mf][nf] = (f32x4){0.f, 0.f, 0.f, 0.f};

    // ---- barrier-free K-loop: A from LDS, B fragments straight from L2 ----
    #pragma unroll
    for (int kt = 0; kt < 10; ++kt) {
        const int k0 = kt * 32;
        bf16x8 bfr[5];
        #pragma unroll
        for (int nf = 0; nf < 5; ++nf)
            bfr[nf] = *(const bf16x8*)&wbt[(size_t)(wn * 80 + nf * 16 + lr) * KPAD + k0 + lg * 8];
        bf16x8 af[4];
        #pragma unroll
        for (int mf = 0; mf < 4; ++mf) {
            bf16x8 a = *(const bf16x8*)&A_lds[(wm * 64 + mf * 16 + lr) * ASTR + k0 + lg * 8];
            if (kt == 9 && lg == 3) a = (bf16x8){};   // cols 312..319 out of row
            af[mf] = a;
        }
        #pragma unroll
        for (int mf = 0; mf < 4; ++mf)
            #pragma unroll
            for (int nf = 0; nf < 5; ++nf)
                acc[mf][nf] = __builtin_amdgcn_mfma_f32_16x16x32_bf16(
                    af[mf], bfr[nf], acc[mf][nf], 0, 0, 0);
    }

    // ---- epilogue: tanh * W_att, reduce over columns ----
    float btv[5], wav[5];
    #pragma unroll
    for (int nf = 0; nf < 5; ++nf) {
        int c = wn * 80 + nf * 16 + lr;
        bool ok = (c < Ddim);
        btv[nf] = ok ? bt[c] : 0.f;
        wav[nf] = ok ? wa[c] : 0.f;
    }
    float sred[4][4];
    #pragma unroll
    for (int mf = 0; mf < 4; ++mf) {
        #pragma unroll
        for (int i = 0; i < 4; ++i) {
            float s = 0.f;
            #pragma unroll
            for (int nf = 0; nf < 5; ++nf)
                s += fast_tanh(acc[mf][nf][i] + btv[nf]) * wav[nf];
            s += __shfl_xor(s, 1, 64);
            s += __shfl_xor(s, 2, 64);
            s += __shfl_xor(s, 4, 64);
            s += __shfl_xor(s, 8, 64);
            sred[mf][i] = s;
        }
    }
    // aux_lds reused as red: every wave is past its idx/A reads of aux only
    // after the K-loop; the sole aux-read in the K-loop (row 127, kt=9, lg=3)
    // is select-masked, so racing writes here are harmless.
    __syncthreads();
    #pragma unroll
    for (int mf = 0; mf < 4; ++mf)
        #pragma unroll
        for (int i = 0; i < 4; ++i)
            if (lr == 0) red_lds[wn][wm * 64 + mf * 16 + lg * 4 + i] = sred[mf][i];
    __syncthreads();
    for (int r = tid; r < BM; r += TPB) {
        float s = ba[0] + red_lds[0][r] + red_lds[1][r] + red_lds[2][r] + red_lds[3][r];
        scores[m0 + r] = s;
    }
}

// ---------------------------------------------------------------------------
// Kernel B: softmax over the TIME axis, in place on the attn region.
// ---------------------------------------------------------------------------
__global__ __launch_bounds__(64) void softmax_time_kernel(float* __restrict__ a)
{
    const int b = blockIdx.x / Pdim;
    const int p = blockIdx.x - b * Pdim;
    const int lane = threadIdx.x;
    const size_t base = (size_t)b * Tdim * Pdim + p;

    float v[4];
    float m = -1e30f;
    #pragma unroll
    for (int i = 0; i < 4; ++i) {
        int t = lane + i * 64;
        v[i] = (t < Tdim) ? a[base + (size_t)t * Pdim] : -1e30f;
        m = fmaxf(m, v[i]);
    }
    #pragma unroll
    for (int off = 32; off > 0; off >>= 1) m = fmaxf(m, __shfl_xor(m, off, 64));

    float s = 0.f;
    #pragma unroll
    for (int i = 0; i < 4; ++i) {
        int t = lane + i * 64;
        if (t < Tdim) { v[i] = expf(v[i] - m); s += v[i]; }
    }
    #pragma unroll
    for (int off = 32; off > 0; off >>= 1) s += __shfl_xor(s, off, 64);

    const float inv = 1.f / s;
    #pragma unroll
    for (int i = 0; i < 4; ++i) {
        int t = lane + i * 64;
        if (t < Tdim) a[base + (size_t)t * Pdim] = v[i] * inv;
    }
}

// ---------------------------------------------------------------------------
// Kernel C+D v4: weights staged to LDS, ALL dot products lane-parallel.
// (unchanged from round 7 -- it left the top-5; don't touch a win)
// ---------------------------------------------------------------------------
template <bool USE_E>
__global__ __launch_bounds__(512, 4) void cvpred4_kernel(
    const float*  __restrict__ x,
    const int*    __restrict__ c2v,
    const float*  __restrict__ en,
    const float*  __restrict__ ep,
    const __bf16* __restrict__ E,
    const float*  __restrict__ attn,
    const float* __restrict__ Wsk, const float* __restrict__ bsk,
    const float* __restrict__ Wkc, const float* __restrict__ bkc,
    const float* __restrict__ Wpr, const float* __restrict__ bpr,
    float* __restrict__ res, float* __restrict__ res2, float* __restrict__ kcm)
{
    const int bt_i = blockIdx.x;           // 0..B*T-1
    const int tid  = threadIdx.x;

    __shared__ float  wsk_lds[Ddim * SKILL];   // 36000 B
    __shared__ float  wkc_lds[Qdim * SKILL];   //  6000 B
    __shared__ float  wpr_lds[SKILL * OUTD];   //  6000 B
    __shared__ int    idx_lds[Pdim * 3];
    __shared__ float  attn_lds[Pdim];
    __shared__ float  x_lds[Qdim];
    __shared__ float4 part_lds[6][76];
    __shared__ float  cv_lds[Ddim];
    __shared__ float  zk_lds[SKILL], o_lds[SKILL], r2_lds[SKILL];

    const int pg = tid / 75;               // 0..6 (6 = inactive)
    const int ch = tid - pg * 75;          // 0..74

    // ---- phase 0: stage weights + per-bt vectors (all independent) ----
    for (int i = tid; i < (Ddim * SKILL) / 4; i += 512)
        ((float4*)wsk_lds)[i] = ((const float4*)Wsk)[i];
    for (int i = tid; i < (Qdim * SKILL) / 4; i += 512)
        ((float4*)wkc_lds)[i] = ((const float4*)Wkc)[i];
    for (int i = tid; i < (SKILL * OUTD) / 4; i += 512)
        ((float4*)wpr_lds)[i] = ((const float4*)Wpr)[i];
    if (!USE_E) {
        if (tid < Pdim * 3) idx_lds[tid] = c2v[(size_t)bt_i * (Pdim * 3) + tid];
    }
    if (tid >= 320 && tid < 320 + Pdim) attn_lds[tid - 320] = attn[(size_t)bt_i * Pdim + tid - 320];
    if (tid >= 448 && tid < 448 + Qdim) x_lds[tid - 448] = x[(size_t)bt_i * Qdim + tid - 448];

    bf16x4 ev[17];
    if (USE_E && pg < 6) {
        const __bf16* base = E + (size_t)bt_i * (Pdim * Ddim) + ch * 4;
        #pragma unroll
        for (int k = 0; k < 17; ++k) {
            int p = pg + 6 * k;
            if (p < Pdim) ev[k] = *(const bf16x4*)(base + p * Ddim);
        }
    }
    __syncthreads();

    // ---- phase 1: weighted sum over p -> part_lds ----
    if (pg < 6) {
        float4 acc = {0.f, 0.f, 0.f, 0.f};
        if (USE_E) {
            #pragma unroll
            for (int k = 0; k < 17; ++k) {
                int p = pg + 6 * k;
                if (p < Pdim) {
                    float a = attn_lds[p];
                    acc.x = fmaf(a, (float)ev[k].x, acc.x);
                    acc.y = fmaf(a, (float)ev[k].y, acc.y);
                    acc.z = fmaf(a, (float)ev[k].z, acc.z);
                    acc.w = fmaf(a, (float)ev[k].w, acc.w);
                }
            }
        } else {
            const int seg = ch / 25, cq = ch - seg * 25;
            const float* tab = (seg == 2) ? ep : en;
            const int io = (seg == 0) ? 0 : (seg == 1) ? 2 : 1;
            int   ri[17];
            float rw[17];
            #pragma unroll
            for (int k = 0; k < 17; ++k) {
                int p = pg + 6 * k;
                bool ok = (p < Pdim);
                ri[k] = idx_lds[(ok ? p : 0) * 3 + io];
                rw[k] = ok ? attn_lds[p] : 0.f;
            }
            {
                float4 va[9];
                #pragma unroll
                for (int k = 0; k < 9; ++k)
                    va[k] = *(const float4*)&tab[(size_t)ri[k] * EMB + cq * 4];
                #pragma unroll
                for (int k = 0; k < 9; ++k) {
                    acc.x = fmaf(rw[k], va[k].x, acc.x);
                    acc.y = fmaf(rw[k], va[k].y, acc.y);
                    acc.z = fmaf(rw[k], va[k].z, acc.z);
                    acc.w = fmaf(rw[k], va[k].w, acc.w);
                }
            }
            {
                float4 vb[8];
                #pragma unroll
                for (int k = 0; k < 8; ++k)
                    vb[k] = *(const float4*)&tab[(size_t)ri[k + 9] * EMB + cq * 4];
                #pragma unroll
                for (int k = 0; k < 8; ++k) {
                    acc.x = fmaf(rw[k + 9], vb[k].x, acc.x);
                    acc.y = fmaf(rw[k + 9], vb[k].y, acc.y);
                    acc.z = fmaf(rw[k + 9], vb[k].z, acc.z);
                    acc.w = fmaf(rw[k + 9], vb[k].w, acc.w);
                }
            }
        }
        part_lds[pg][ch] = acc;
    }
    __syncthreads();

    // ---- phase 2: reduce 6 p-groups -> cv_lds ----
    if (tid < 75) {
        float4 a0 = part_lds[0][tid], a1 = part_lds[1][tid];
        float4 a2 = part_lds[2][tid], a3 = part_lds[3][tid];
        float4 a4 = part_lds[4][tid], a5 = part_lds[5][tid];
        int c = tid * 4;
        cv_lds[c + 0] = a0.x + a1.x + a2.x + a3.x + a4.x + a5.x;
        cv_lds[c + 1] = a0.y + a1.y + a2.y + a3.y + a4.y + a5.y;
        cv_lds[c + 2] = a0.z + a1.z + a2.z + a3.z + a4.z + a5.z;
        cv_lds[c + 3] = a0.w + a1.w + a2.w + a3.w + a4.w + a5.w;
    }
    __syncthreads();

    // ---- phase 3: lane-parallel dot products (all LDS reads) ----
    if (tid < 480) {                       // o[s] = cv . Wsk[:,s]  (30 x 16)
        const int s = tid >> 4, l = tid & 15;
        float o = 0.f;
        #pragma unroll
        for (int j = 0; j < 19; ++j) {
            int c = l + 16 * j;
            if (c < Ddim) o = fmaf(cv_lds[c], wsk_lds[c * SKILL + s], o);
        }
        o += __shfl_xor(o, 8, 64);
        o += __shfl_xor(o, 4, 64);
        o += __shfl_xor(o, 2, 64);
        o += __shfl_xor(o, 1, 64);
        if (l == 0) o_lds[s] = o + bsk[s];
    }
    if (tid < 240) {                       // zk[s] = x . Wkc[:,s]  (30 x 8)
        const int s = tid >> 3, l = tid & 7;
        float zk = 0.f;
        #pragma unroll
        for (int j = 0; j < 7; ++j) {
            int q = l + 8 * j;
            if (q < Qdim) zk = fmaf(x_lds[q], wkc_lds[q * SKILL + s], zk);
        }
        zk += __shfl_xor(zk, 4, 64);
        zk += __shfl_xor(zk, 2, 64);
        zk += __shfl_xor(zk, 1, 64);
        if (l == 0) zk_lds[s] = zk + bkc[s];
    }
    __syncthreads();

    // ---- phase 4: gate + writes ----
    if (tid < SKILL) {
        float zk = zk_lds[tid];
        float r2 = (zk >= 0.f) ? o_lds[tid] : 0.f;  // sigmoid(zk)>=0.5 <=> zk>=0
        kcm [(size_t)bt_i * SKILL + tid] = sigmoidf_(zk);
        res2[(size_t)bt_i * SKILL + tid] = r2;
        r2_lds[tid] = r2;
    }
    __syncthreads();

    // ---- phase 5: res[o] = sigmoid(r2 . Wpr[:,o] + bpr)  (50 x 8) ----
    if (tid < 400) {
        const int od = tid >> 3, l = tid & 7;
        float z = 0.f;
        #pragma unroll
        for (int j = 0; j < 4; ++j) {
            int s = l + 8 * j;
            if (s < SKILL) z = fmaf(r2_lds[s], wpr_lds[s * OUTD + od], z);
        }
        z += __shfl_xor(z, 4, 64);
        z += __shfl_xor(z, 2, 64);
        z += __shfl_xor(z, 1, 64);
        if (l == 0) res[(size_t)bt_i * OUTD + od] = sigmoidf_(z + bpr[od]);
    }
}

// ---------------------------------------------------------------------------
extern "C" void kernel_launch(void* const* d_in, const int* in_sizes, int n_in,
                              void* d_out, int out_size, void* d_ws, size_t ws_size,
                              hipStream_t stream)
{
    const float* x   = (const float*)d_in[0];
    const int*   c2v = (const int*)  d_in[1];
    const float* en  = (const float*)d_in[2];
    const float* ep  = (const float*)d_in[3];
    const float* Wt  = (const float*)d_in[4];
    const float* bt  = (const float*)d_in[5];
    const float* Wa  = (const float*)d_in[6];
    const float* ba  = (const float*)d_in[7];
    const float* Wsk = (const float*)d_in[8];
    const float* bsk = (const float*)d_in[9];
    const float* Wkc = (const float*)d_in[10];
    const float* bkc = (const float*)d_in[11];
    const float* Wpr = (const float*)d_in[12];
    const float* bpr = (const float*)d_in[13];

    float* out  = (float*)d_out;
    float* res  = out + OFF_RES;
    float* res2 = out + OFF_RES2;
    float* kcm  = out + OFF_KC;
    float* attn = out + OFF_ATTN;

    __bf16* wbt  = (__bf16*)d_ws;                       // 204800 B
    __bf16* e_ws = (__bf16*)((char*)d_ws + WBT_BYTES);  // 192 MB bf16 E spill

    const bool use_e = ws_size >= WBT_BYTES + E_BYTES;

    prep_wbt_kernel<<<(KPAD * KPAD + 255) / 256, 256, 0, stream>>>(Wt, wbt);

    if (use_e)
        score_mfma_kernel<true><<<NROWS / BM, TPB, 0, stream>>>(
            c2v, en, ep, wbt, bt, Wa, ba, attn, e_ws);
    else
        score_mfma_kernel<false><<<NROWS / BM, TPB, 0, stream>>>(
            c2v, en, ep, wbt, bt, Wa, ba, attn, e_ws);

    softmax_time_kernel<<<Bdim * Pdim, 64, 0, stream>>>(attn);

    if (use_e)
        cvpred4_kernel<true><<<Bdim * Tdim, 512, 0, stream>>>(
            x, c2v, en, ep, e_ws, attn, Wsk, bsk, Wkc, bkc, Wpr, bpr, res, res2, kcm);
    else
        cvpred4_kernel<false><<<Bdim * Tdim, 512, 0, stream>>>(
            x, c2v, en, ep, e_ws, attn, Wsk, bsk, Wkc, bkc, Wpr, bpr, res, res2, kcm);
}

// Round 9
// 327.984 us; speedup vs baseline: 2.5157x; 1.0798x over previous
//
#include <hip/hip_runtime.h>
#include <hip/hip_bf16.h>
#include <math.h>

#define Bdim 16
#define Tdim 200
#define Pdim 100
#define EMB  100
#define Ddim 300
#define SKILL 30
#define Qdim 50
#define OUTD 50

// d_out layout (floats), concatenated in reference return order:
// res [B,T,50], res2 [B,T,30], kc_mask [B,T,30], attn [B,T,P,1]
#define OFF_RES   0
#define OFF_RES2  (Bdim*Tdim*OUTD)              // 160000
#define OFF_KC    (OFF_RES2 + Bdim*Tdim*SKILL)  // 256000
#define OFF_ATTN  (OFF_KC + Bdim*Tdim*SKILL)    // 352000

typedef __bf16 bf16x8 __attribute__((ext_vector_type(8)));
typedef __bf16 bf16x4 __attribute__((ext_vector_type(4)));
typedef float  f32x4  __attribute__((ext_vector_type(4)));

// MFMA geometry for the score GEMM
#define BM    128          // rows per block
#define KPAD  320          // padded K (and padded N) of wbt
#define ASTR  312          // A row stride in bf16 (624 B)
#define TPB   512          // 8 waves

#define EROW  320          // E spill row stride in bf16 (640 B = 10 L2 lines)

#define NROWS (Bdim*Tdim*Pdim)                  // 320000
#define WBT_BYTES ((size_t)KPAD*KPAD*2)         // 204800
#define E_BYTES   ((size_t)NROWS*EROW*2)        // 204,800,000

__device__ __forceinline__ float fast_tanh(float x) {
    float t = __expf(2.0f * x);
    return 1.0f - 2.0f * __builtin_amdgcn_rcpf(t + 1.0f);
}
__device__ __forceinline__ float sigmoidf_(float z) {
    return 1.f / (1.f + expf(-z));
}

// ---------------------------------------------------------------------------
// Prep: W_trans (300x300 fp32, row-major [k][j]) -> bf16 TRANSPOSED padded
// wbt[j][k], zeros outside 300 (both j and k) -- the k-pad zeros make the
// A-side pad/garbage reads harmless in the GEMM.
// ---------------------------------------------------------------------------
__global__ __launch_bounds__(256) void prep_wbt_kernel(
    const float* __restrict__ Wt, __bf16* __restrict__ wbt)
{
    int id = blockIdx.x * 256 + threadIdx.x;
    if (id >= KPAD * KPAD) return;
    int j = id / KPAD, k = id - j * KPAD;
    float v = (j < Ddim && k < Ddim) ? Wt[k * Ddim + j] : 0.0f;
    wbt[id] = (__bf16)v;
}

// ---------------------------------------------------------------------------
// Kernel A (MFMA): raw attention scores; bf16 E spill (row stride 320) to ws.
// score[m] = tanh(E[m] @ W_trans + b_trans) @ W_att + b_att
// Structure: no B_lds (B fragments straight from L2-resident wbt),
// barrier-free K-loop, 80 KB LDS -> 2 blocks/CU, VALU-lean gather
// (thread = (row, quarter), pure imm-offset loads, register-batched).
// ---------------------------------------------------------------------------
template <bool WRITE_E>
__global__ __launch_bounds__(TPB, 4) void score_mfma_kernel(
    const int*    __restrict__ c2v,
    const float*  __restrict__ en,
    const float*  __restrict__ ep,
    const __bf16* __restrict__ wbt,
    const float*  __restrict__ bt,
    const float*  __restrict__ wa,
    const float*  __restrict__ ba,
    float* __restrict__ scores,
    __bf16* __restrict__ e_out)
{
    __shared__ __align__(16) __bf16 A_lds[BM * ASTR];   // 79872 B
    __shared__ __align__(16) char   aux_lds[2048];      // idx (early) / red (late)
    int*  idx_lds = (int*)aux_lds;                      // [BM*3] = 1536 B
    float (*red_lds)[BM] = (float (*)[BM])aux_lds;      // [4][BM] = 2048 B

    const int tid = threadIdx.x;
    const int m0  = blockIdx.x * BM;

    if (tid < BM * 3) idx_lds[tid] = c2v[(size_t)m0 * 3 + tid];
    __syncthreads();

    // ---- gather fp32 embeddings -> bf16 A tile (VALU-lean) ----
    {
        const int r   = tid >> 2;        // 0..127: one row per 4 threads
        const int sub = tid & 3;         // quarter of the row
        const int i0 = idx_lds[r * 3 + 0];
        const int i1 = idx_lds[r * 3 + 1];
        const int i2 = idx_lds[r * 3 + 2];
        __bf16* arow = &A_lds[r * ASTR];
        const float* srcs[3] = { en + (size_t)i0 * EMB,     // cols   0- 99
                                 en + (size_t)i2 * EMB,     // cols 100-199
                                 ep + (size_t)i1 * EMB };   // cols 200-299
        #pragma unroll
        for (int seg = 0; seg < 3; ++seg) {
            const float* src = srcs[seg];
            float4 v[7];
            #pragma unroll
            for (int k = 0; k < 7; ++k) {
                int j = sub + 4 * k;
                if (j < 25) v[k] = *(const float4*)(src + j * 4);
            }
            #pragma unroll
            for (int k = 0; k < 7; ++k) {
                int j = sub + 4 * k;
                if (j < 25) {
                    float4 w = v[k];
                    bf16x4 b4 = { (__bf16)w.x, (__bf16)w.y, (__bf16)w.z, (__bf16)w.w };
                    *(bf16x4*)(arow + seg * 100 + j * 4) = b4;
                }
            }
        }
        // zero pad cols 300..311 (NaN hygiene for the K-loop's last tile)
        if (sub < 3) *(bf16x4*)(arow + 300 + sub * 4) = (bf16x4){};
    }
    __syncthreads();

    // ---- spill bf16 E tile (640 B-aligned rows; fire-and-forget) ----
    if (WRITE_E) {
        #pragma unroll
        for (int pos = tid; pos < BM * 40; pos += TPB) {
            int r = pos / 40, q = pos - r * 40;
            // q=39 reads 8 elems past the 312-wide row (next row / aux junk);
            // it lands in E pad cols 312..319 which are never read back.
            bf16x8 v = *(const bf16x8*)&A_lds[r * ASTR + q * 8];
            *(bf16x8*)&e_out[(size_t)(m0 + r) * EROW + q * 8] = v;
        }
    }

    const int wid = tid >> 6, lane = tid & 63;
    const int wm = wid >> 2, wn = wid & 3;       // 2 x 4 wave grid
    const int lr = lane & 15, lg = lane >> 4;

    f32x4 acc[4][5];
    #pragma unroll
    for (int mf = 0; mf < 4; ++mf)
        #pragma unroll
        for (int nf = 0; nf < 5; ++nf) acc[mf][nf] = (f32x4){0.f, 0.f, 0.f, 0.f};

    // ---- barrier-free K-loop: A from LDS, B fragments straight from L2 ----
    #pragma unroll
    for (int kt = 0; kt < 10; ++kt) {
        const int k0 = kt * 32;
        bf16x8 bfr[5];
        #pragma unroll
        for (int nf = 0; nf < 5; ++nf)
            bfr[nf] = *(const bf16x8*)&wbt[(size_t)(wn * 80 + nf * 16 + lr) * KPAD + k0 + lg * 8];
        bf16x8 af[4];
        #pragma unroll
        for (int mf = 0; mf < 4; ++mf) {
            bf16x8 a = *(const bf16x8*)&A_lds[(wm * 64 + mf * 16 + lr) * ASTR + k0 + lg * 8];
            if (kt == 9 && lg == 3) a = (bf16x8){};   // cols 312..319: out of row
            af[mf] = a;
        }
        #pragma unroll
        for (int mf = 0; mf < 4; ++mf)
            #pragma unroll
            for (int nf = 0; nf < 5; ++nf)
                acc[mf][nf] = __builtin_amdgcn_mfma_f32_16x16x32_bf16(
                    af[mf], bfr[nf], acc[mf][nf], 0, 0, 0);
    }

    // ---- epilogue: tanh * W_att, reduce over columns ----
    float btv[5], wav[5];
    #pragma unroll
    for (int nf = 0; nf < 5; ++nf) {
        int c = wn * 80 + nf * 16 + lr;
        bool ok = (c < Ddim);
        btv[nf] = ok ? bt[c] : 0.f;
        wav[nf] = ok ? wa[c] : 0.f;
    }
    float sred[4][4];
    #pragma unroll
    for (int mf = 0; mf < 4; ++mf) {
        #pragma unroll
        for (int i = 0; i < 4; ++i) {
            float s = 0.f;
            #pragma unroll
            for (int nf = 0; nf < 5; ++nf)
                s += fast_tanh(acc[mf][nf][i] + btv[nf]) * wav[nf];
            s += __shfl_xor(s, 1, 64);
            s += __shfl_xor(s, 2, 64);
            s += __shfl_xor(s, 4, 64);
            s += __shfl_xor(s, 8, 64);
            sred[mf][i] = s;
        }
    }
    // aux_lds reused as red_lds: all aux reads (idx) completed pre-K-loop;
    // the lone in-loop aux-adjacent read (row 127, kt=9, lg=3) is masked.
    __syncthreads();
    #pragma unroll
    for (int mf = 0; mf < 4; ++mf)
        #pragma unroll
        for (int i = 0; i < 4; ++i)
            if (lr == 0) red_lds[wn][wm * 64 + mf * 16 + lg * 4 + i] = sred[mf][i];
    __syncthreads();
    for (int r = tid; r < BM; r += TPB) {
        float s = ba[0] + red_lds[0][r] + red_lds[1][r] + red_lds[2][r] + red_lds[3][r];
        scores[m0 + r] = s;
    }
}

// ---------------------------------------------------------------------------
// Kernel B: softmax over the TIME axis, in place on the attn region.
// ---------------------------------------------------------------------------
__global__ __launch_bounds__(64) void softmax_time_kernel(float* __restrict__ a)
{
    const int b = blockIdx.x / Pdim;
    const int p = blockIdx.x - b * Pdim;
    const int lane = threadIdx.x;
    const size_t base = (size_t)b * Tdim * Pdim + p;

    float v[4];
    float m = -1e30f;
    #pragma unroll
    for (int i = 0; i < 4; ++i) {
        int t = lane + i * 64;
        v[i] = (t < Tdim) ? a[base + (size_t)t * Pdim] : -1e30f;
        m = fmaxf(m, v[i]);
    }
    #pragma unroll
    for (int off = 32; off > 0; off >>= 1) m = fmaxf(m, __shfl_xor(m, off, 64));

    float s = 0.f;
    #pragma unroll
    for (int i = 0; i < 4; ++i) {
        int t = lane + i * 64;
        if (t < Tdim) { v[i] = expf(v[i] - m); s += v[i]; }
    }
    #pragma unroll
    for (int off = 32; off > 0; off >>= 1) s += __shfl_xor(s, off, 64);

    const float inv = 1.f / s;
    #pragma unroll
    for (int i = 0; i < 4; ++i) {
        int t = lane + i * 64;
        if (t < Tdim) a[base + (size_t)t * Pdim] = v[i] * inv;
    }
}

// ---------------------------------------------------------------------------
// Kernel C+D v4: weights staged to LDS, ALL dot products lane-parallel.
// (structure unchanged from the round-7 win; only E row stride -> 320)
// ---------------------------------------------------------------------------
template <bool USE_E>
__global__ __launch_bounds__(512, 4) void cvpred4_kernel(
    const float*  __restrict__ x,
    const int*    __restrict__ c2v,
    const float*  __restrict__ en,
    const float*  __restrict__ ep,
    const __bf16* __restrict__ E,
    const float*  __restrict__ attn,
    const float* __restrict__ Wsk, const float* __restrict__ bsk,
    const float* __restrict__ Wkc, const float* __restrict__ bkc,
    const float* __restrict__ Wpr, const float* __restrict__ bpr,
    float* __restrict__ res, float* __restrict__ res2, float* __restrict__ kcm)
{
    const int bt_i = blockIdx.x;           // 0..B*T-1
    const int tid  = threadIdx.x;

    __shared__ float  wsk_lds[Ddim * SKILL];   // 36000 B
    __shared__ float  wkc_lds[Qdim * SKILL];   //  6000 B
    __shared__ float  wpr_lds[SKILL * OUTD];   //  6000 B
    __shared__ int    idx_lds[Pdim * 3];
    __shared__ float  attn_lds[Pdim];
    __shared__ float  x_lds[Qdim];
    __shared__ float4 part_lds[6][76];
    __shared__ float  cv_lds[Ddim];
    __shared__ float  zk_lds[SKILL], o_lds[SKILL], r2_lds[SKILL];

    const int pg = tid / 75;               // 0..6 (6 = inactive)
    const int ch = tid - pg * 75;          // 0..74

    // ---- phase 0: stage weights + per-bt vectors (all independent) ----
    for (int i = tid; i < (Ddim * SKILL) / 4; i += 512)
        ((float4*)wsk_lds)[i] = ((const float4*)Wsk)[i];
    for (int i = tid; i < (Qdim * SKILL) / 4; i += 512)
        ((float4*)wkc_lds)[i] = ((const float4*)Wkc)[i];
    for (int i = tid; i < (SKILL * OUTD) / 4; i += 512)
        ((float4*)wpr_lds)[i] = ((const float4*)Wpr)[i];
    if (!USE_E) {
        if (tid < Pdim * 3) idx_lds[tid] = c2v[(size_t)bt_i * (Pdim * 3) + tid];
    }
    if (tid >= 320 && tid < 320 + Pdim) attn_lds[tid - 320] = attn[(size_t)bt_i * Pdim + tid - 320];
    if (tid >= 448 && tid < 448 + Qdim) x_lds[tid - 448] = x[(size_t)bt_i * Qdim + tid - 448];

    bf16x4 ev[17];
    if (USE_E && pg < 6) {
        const __bf16* base = E + (size_t)bt_i * (Pdim * EROW) + ch * 4;
        #pragma unroll
        for (int k = 0; k < 17; ++k) {
            int p = pg + 6 * k;
            if (p < Pdim) ev[k] = *(const bf16x4*)(base + p * EROW);
        }
    }
    __syncthreads();

    // ---- phase 1: weighted sum over p -> part_lds ----
    if (pg < 6) {
        float4 acc = {0.f, 0.f, 0.f, 0.f};
        if (USE_E) {
            #pragma unroll
            for (int k = 0; k < 17; ++k) {
                int p = pg + 6 * k;
                if (p < Pdim) {
                    float a = attn_lds[p];
                    acc.x = fmaf(a, (float)ev[k].x, acc.x);
                    acc.y = fmaf(a, (float)ev[k].y, acc.y);
                    acc.z = fmaf(a, (float)ev[k].z, acc.z);
                    acc.w = fmaf(a, (float)ev[k].w, acc.w);
                }
            }
        } else {
            const int seg = ch / 25, cq = ch - seg * 25;
            const float* tab = (seg == 2) ? ep : en;
            const int io = (seg == 0) ? 0 : (seg == 1) ? 2 : 1;
            int   ri[17];
            float rw[17];
            #pragma unroll
            for (int k = 0; k < 17; ++k) {
                int p = pg + 6 * k;
                bool ok = (p < Pdim);
                ri[k] = idx_lds[(ok ? p : 0) * 3 + io];
                rw[k] = ok ? attn_lds[p] : 0.f;
            }
            {
                float4 va[9];
                #pragma unroll
                for (int k = 0; k < 9; ++k)
                    va[k] = *(const float4*)&tab[(size_t)ri[k] * EMB + cq * 4];
                #pragma unroll
                for (int k = 0; k < 9; ++k) {
                    acc.x = fmaf(rw[k], va[k].x, acc.x);
                    acc.y = fmaf(rw[k], va[k].y, acc.y);
                    acc.z = fmaf(rw[k], va[k].z, acc.z);
                    acc.w = fmaf(rw[k], va[k].w, acc.w);
                }
            }
            {
                float4 vb[8];
                #pragma unroll
                for (int k = 0; k < 8; ++k)
                    vb[k] = *(const float4*)&tab[(size_t)ri[k + 9] * EMB + cq * 4];
                #pragma unroll
                for (int k = 0; k < 8; ++k) {
                    acc.x = fmaf(rw[k + 9], vb[k].x, acc.x);
                    acc.y = fmaf(rw[k + 9], vb[k].y, acc.y);
                    acc.z = fmaf(rw[k + 9], vb[k].z, acc.z);
                    acc.w = fmaf(rw[k + 9], vb[k].w, acc.w);
                }
            }
        }
        part_lds[pg][ch] = acc;
    }
    __syncthreads();

    // ---- phase 2: reduce 6 p-groups -> cv_lds ----
    if (tid < 75) {
        float4 a0 = part_lds[0][tid], a1 = part_lds[1][tid];
        float4 a2 = part_lds[2][tid], a3 = part_lds[3][tid];
        float4 a4 = part_lds[4][tid], a5 = part_lds[5][tid];
        int c = tid * 4;
        cv_lds[c + 0] = a0.x + a1.x + a2.x + a3.x + a4.x + a5.x;
        cv_lds[c + 1] = a0.y + a1.y + a2.y + a3.y + a4.y + a5.y;
        cv_lds[c + 2] = a0.z + a1.z + a2.z + a3.z + a4.z + a5.z;
        cv_lds[c + 3] = a0.w + a1.w + a2.w + a3.w + a4.w + a5.w;
    }
    __syncthreads();

    // ---- phase 3: lane-parallel dot products (all LDS reads) ----
    if (tid < 480) {                       // o[s] = cv . Wsk[:,s]  (30 x 16)
        const int s = tid >> 4, l = tid & 15;
        float o = 0.f;
        #pragma unroll
        for (int j = 0; j < 19; ++j) {
            int c = l + 16 * j;
            if (c < Ddim) o = fmaf(cv_lds[c], wsk_lds[c * SKILL + s], o);
        }
        o += __shfl_xor(o, 8, 64);
        o += __shfl_xor(o, 4, 64);
        o += __shfl_xor(o, 2, 64);
        o += __shfl_xor(o, 1, 64);
        if (l == 0) o_lds[s] = o + bsk[s];
    }
    if (tid < 240) {                       // zk[s] = x . Wkc[:,s]  (30 x 8)
        const int s = tid >> 3, l = tid & 7;
        float zk = 0.f;
        #pragma unroll
        for (int j = 0; j < 7; ++j) {
            int q = l + 8 * j;
            if (q < Qdim) zk = fmaf(x_lds[q], wkc_lds[q * SKILL + s], zk);
        }
        zk += __shfl_xor(zk, 4, 64);
        zk += __shfl_xor(zk, 2, 64);
        zk += __shfl_xor(zk, 1, 64);
        if (l == 0) zk_lds[s] = zk + bkc[s];
    }
    __syncthreads();

    // ---- phase 4: gate + writes ----
    if (tid < SKILL) {
        float zk = zk_lds[tid];
        float r2 = (zk >= 0.f) ? o_lds[tid] : 0.f;  // sigmoid(zk)>=0.5 <=> zk>=0
        kcm [(size_t)bt_i * SKILL + tid] = sigmoidf_(zk);
        res2[(size_t)bt_i * SKILL + tid] = r2;
        r2_lds[tid] = r2;
    }
    __syncthreads();

    // ---- phase 5: res[o] = sigmoid(r2 . Wpr[:,o] + bpr)  (50 x 8) ----
    if (tid < 400) {
        const int od = tid >> 3, l = tid & 7;
        float z = 0.f;
        #pragma unroll
        for (int j = 0; j < 4; ++j) {
            int s = l + 8 * j;
            if (s < SKILL) z = fmaf(r2_lds[s], wpr_lds[s * OUTD + od], z);
        }
        z += __shfl_xor(z, 4, 64);
        z += __shfl_xor(z, 2, 64);
        z += __shfl_xor(z, 1, 64);
        if (l == 0) res[(size_t)bt_i * OUTD + od] = sigmoidf_(z + bpr[od]);
    }
}

// ---------------------------------------------------------------------------
extern "C" void kernel_launch(void* const* d_in, const int* in_sizes, int n_in,
                              void* d_out, int out_size, void* d_ws, size_t ws_size,
                              hipStream_t stream)
{
    const float* x   = (const float*)d_in[0];
    const int*   c2v = (const int*)  d_in[1];
    const float* en  = (const float*)d_in[2];
    const float* ep  = (const float*)d_in[3];
    const float* Wt  = (const float*)d_in[4];
    const float* bt  = (const float*)d_in[5];
    const float* Wa  = (const float*)d_in[6];
    const float* ba  = (const float*)d_in[7];
    const float* Wsk = (const float*)d_in[8];
    const float* bsk = (const float*)d_in[9];
    const float* Wkc = (const float*)d_in[10];
    const float* bkc = (const float*)d_in[11];
    const float* Wpr = (const float*)d_in[12];
    const float* bpr = (const float*)d_in[13];

    float* out  = (float*)d_out;
    float* res  = out + OFF_RES;
    float* res2 = out + OFF_RES2;
    float* kcm  = out + OFF_KC;
    float* attn = out + OFF_ATTN;

    __bf16* wbt  = (__bf16*)d_ws;                       // 204800 B
    __bf16* e_ws = (__bf16*)((char*)d_ws + WBT_BYTES);  // 204.8 MB bf16 E spill

    const bool use_e = ws_size >= WBT_BYTES + E_BYTES;

    prep_wbt_kernel<<<(KPAD * KPAD + 255) / 256, 256, 0, stream>>>(Wt, wbt);

    if (use_e)
        score_mfma_kernel<true><<<NROWS / BM, TPB, 0, stream>>>(
            c2v, en, ep, wbt, bt, Wa, ba, attn, e_ws);
    else
        score_mfma_kernel<false><<<NROWS / BM, TPB, 0, stream>>>(
            c2v, en, ep, wbt, bt, Wa, ba, attn, e_ws);

    softmax_time_kernel<<<Bdim * Pdim, 64, 0, stream>>>(attn);

    if (use_e)
        cvpred4_kernel<true><<<Bdim * Tdim, 512, 0, stream>>>(
            x, c2v, en, ep, e_ws, attn, Wsk, bsk, Wkc, bkc, Wpr, bpr, res, res2, kcm);
    else
        cvpred4_kernel<false><<<Bdim * Tdim, 512, 0, stream>>>(
            x, c2v, en, ep, e_ws, attn, Wsk, bsk, Wkc, bkc, Wpr, bpr, res, res2, kcm);
}